// Round 9
// baseline (348.459 us; speedup 1.0000x reference)
//
#include <hip/hip_runtime.h>
#include <stdint.h>

#define B_ 4
#define S_ 2048
#define E_ 1024
#define D_ 1024   // attention dim

typedef short  bf16x8 __attribute__((ext_vector_type(8)));
typedef float  f32x4  __attribute__((ext_vector_type(4)));

// fp32 -> bf16 round-to-nearest-even
static __device__ __forceinline__ unsigned short f2bf(float f) {
    unsigned int u = __float_as_uint(f);
    u += 0x7fffu + ((u >> 16) & 1u);
    return (unsigned short)(u >> 16);
}

// async global->LDS, 16B per lane. LDS dest = wave-uniform base + lane*16.
static __device__ __forceinline__ void async16(const unsigned short* g, unsigned short* l) {
    auto gp = (const __attribute__((address_space(1))) void*)(uintptr_t)g;
    auto lp = (__attribute__((address_space(3))) void*)(uintptr_t)l;
    __builtin_amdgcn_global_load_lds(gp, lp, 16, 0, 0);
}

// ---------------------------------------------------------------------------
// LDS sub-tile unit (BK=64): row = 128 B = 8 chunks of 16 B. XOR swizzle:
// global chunk q of row r -> LDS chunk q^(r&7). One async16 covers 8 rows:
// lane l -> row +(l>>3), global chunk (l&7)^(l>>3). Reader k-half s reads
// chunk (s*4+quad)^(r&7). Conflict-free (SQ_LDS_BANK_CONFLICT=0, measured).
//
// R9: R8's absmax error (2.06 = max|ref|) is the signature of out never
// written: hipLaunchCooperativeKernel failed under graph capture (unchecked
// rc) and attn never ran. Cooperative launch is NOT needed — co-residency is
// guaranteed by capacity: 32 KB LDS -> 5 blocks/CU, 4 waves@64VGPR -> 8
// blocks/CU => min 5 >= 4 needed; 4/CU x 256 CU = 1024 = grid, all blocks
// resident, handshake deadlock-free under any dispatch order (exp blocks
// 0..543 never wait; in-order dispatch also puts them first). Plain launch.
// Cross-XCD visibility inside ONE dispatch is explicit: producer thread0
// does __threadfence (agent fence: L2 writeback) before the RELEASE
// atomicAdd; consumer thread0 spins with ACQUIRE loads then __threadfence
// (L1/L2 invalidate) before the block touches P/rowpart.
// ---------------------------------------------------------------------------

// Kernel 0: fp32 -> bf16 convert (x -> xb, [Wk;Wq;Wv] -> Wb). Grid-stride.
// Also zeroes the done[] counters used by attn_kernel.
__global__ __launch_bounds__(256)
void convert_kernel(const float* __restrict__ x,  const float* __restrict__ Wk,
                    const float* __restrict__ Wq, const float* __restrict__ Wv,
                    unsigned short* __restrict__ xb, unsigned short* __restrict__ Wb,
                    int* __restrict__ done)
{
    if (blockIdx.x == 0 && threadIdx.x < 64) done[threadIdx.x] = 0;

    const long long total  = (long long)B_ * S_ * E_ + 3LL * D_ * E_;  // 11534336
    const long long stride = (long long)gridDim.x * 256 * 4;
    for (long long idx = ((long long)blockIdx.x * 256 + threadIdx.x) * 4;
         idx < total; idx += stride) {
        const float* src; unsigned short* dst; long long off;
        if (idx < (long long)B_ * S_ * E_) {
            src = x; dst = xb; off = idx;
        } else {
            long long w = idx - (long long)B_ * S_ * E_;
            const int sel = (int)(w >> 20);          // 2^20 elems per W
            off = w & 1048575LL;
            src = (sel == 0) ? Wk : (sel == 1) ? Wq : Wv;
            dst = Wb + ((long long)sel << 20);
        }
        const float4 f = *(const float4*)(src + off);
        ushort4 u = { f2bf(f.x), f2bf(f.y), f2bf(f.z), f2bf(f.w) };
        *(ushort4*)(dst + off) = u;
    }
}

// ---------------------------------------------------------------------------
// Kernel 1: projections (FROZEN — 916 TF m97 plateau, 4 blocks/CU implicit
// overlap). C[m,n] = sum_e xb[m,e]*Wb[n,e]. Grid (64 m FAST, 24 ny).
// ---------------------------------------------------------------------------
__global__ __launch_bounds__(256, 4)
void proj_kernel(const unsigned short* __restrict__ xb,
                 const unsigned short* __restrict__ Wb,
                 unsigned short* __restrict__ Qb,
                 unsigned short* __restrict__ Kb,
                 unsigned short* __restrict__ Vt)
{
    __shared__ __align__(16) unsigned short As[128 * 64];
    __shared__ __align__(16) unsigned short Bs[128 * 64];

    const int t    = threadIdx.x;
    const int m0   = blockIdx.x * 128;
    const int ny   = blockIdx.y;
    const int wsel = ny >> 3;
    const int nloc = (ny & 7) * 128;

    const int lane = t & 63, wave = t >> 6;
    const int l15 = lane & 15, quad = lane >> 4;
    const int wm = wave & 1, wn = wave >> 1;
    const int sr = lane >> 3;
    const int sq = ((lane & 7) ^ sr) * 8;
    const int l7 = l15 & 7;
    const int rcA0 = (wm * 64 + l15) * 64 + ((quad ^ l7) * 8);
    const int rcA1 = (wm * 64 + l15) * 64 + (((4 + quad) ^ l7) * 8);
    const int rcB0 = (wn * 64 + l15) * 64 + ((quad ^ l7) * 8);
    const int rcB1 = (wn * 64 + l15) * 64 + (((4 + quad) ^ l7) * 8);

    const unsigned short* gA = xb + (size_t)(m0 + wave * 32 + sr) * E_ + sq;
    const unsigned short* gB = Wb + (size_t)(ny * 128 + wave * 32 + sr) * E_ + sq;
    unsigned short* lA = &As[wave * 2048];
    unsigned short* lB = &Bs[wave * 2048];

    f32x4 acc[4][4];
    #pragma unroll
    for (int i = 0; i < 4; i++)
        #pragma unroll
        for (int j = 0; j < 4; j++) acc[i][j] = {0.f, 0.f, 0.f, 0.f};

    for (int k0 = 0; k0 < E_; k0 += 64) {
        __syncthreads();
        #pragma unroll
        for (int i = 0; i < 4; i++) {
            async16(gA + k0 + i * 8 * E_, lA + i * 512);
            async16(gB + k0 + i * 8 * E_, lB + i * 512);
        }
        __syncthreads();

        #pragma unroll
        for (int s = 0; s < 2; s++) {
            bf16x8 af[4], bfr[4];
            const int ra = s ? rcA1 : rcA0, rb = s ? rcB1 : rcB0;
            #pragma unroll
            for (int i = 0; i < 4; i++) af[i]  = *(const bf16x8*)&As[ra + i * 1024];
            #pragma unroll
            for (int j = 0; j < 4; j++) bfr[j] = *(const bf16x8*)&Bs[rb + j * 1024];
            #pragma unroll
            for (int i = 0; i < 4; i++)
                #pragma unroll
                for (int j = 0; j < 4; j++)
                    acc[i][j] = __builtin_amdgcn_mfma_f32_16x16x32_bf16(af[i], bfr[j], acc[i][j], 0, 0, 0);
        }
    }

    if (wsel == 0) {
        #pragma unroll
        for (int i = 0; i < 4; i++)
            #pragma unroll
            for (int j = 0; j < 4; j++) {
                const int gn = nloc + wn * 64 + j * 16 + l15;
                #pragma unroll
                for (int r = 0; r < 4; r++) {
                    const int gm = m0 + wm * 64 + i * 16 + quad * 4 + r;
                    Kb[(size_t)gm * D_ + gn] = f2bf(acc[i][j][r]);
                }
            }
    } else if (wsel == 1) {
        #pragma unroll
        for (int i = 0; i < 4; i++)
            #pragma unroll
            for (int j = 0; j < 4; j++) {
                const int gn = nloc + wn * 64 + j * 16 + l15;
                #pragma unroll
                for (int r = 0; r < 4; r++) {
                    const int gm = m0 + wm * 64 + i * 16 + quad * 4 + r;
                    Qb[(size_t)gm * D_ + gn] = f2bf(acc[i][j][r] * 0.03125f);
                }
            }
    } else {
        #pragma unroll
        for (int i = 0; i < 4; i++)
            #pragma unroll
            for (int j = 0; j < 4; j++) {
                const int s0 = m0 + wm * 64 + i * 16 + quad * 4;
                const int b  = s0 >> 11, sl = s0 & (S_ - 1);
                const int gn = nloc + wn * 64 + j * 16 + l15;
                ushort4 u = { f2bf(acc[i][j][0]), f2bf(acc[i][j][1]),
                              f2bf(acc[i][j][2]), f2bf(acc[i][j][3]) };
                *(ushort4*)&Vt[((size_t)(b << 10) + gn) * S_ + sl] = u;
            }
    }
}

// ---------------------------------------------------------------------------
// exp tile: E = exp(Qs K^T), causal, bf16 -> P. 128x128, BK=64, single-buf
// 32 KB. Identical to the R4 expscores body. Signals done[b*16+mt] on exit
// (agent fence + release atomic).
// ---------------------------------------------------------------------------
static __device__ __forceinline__
void do_exp(int g, const unsigned short* Qb, const unsigned short* Kb,
            unsigned short* P, float* rowpart, int* done,
            unsigned short* As, unsigned short* Bs)
{
    const int b = g & 3;
    int rem = g >> 2;                 // 0..135, heavy-first
    int mt = 15, cnt = 16;
    while (rem >= cnt) { rem -= cnt; mt--; cnt--; }
    const int nt = rem;

    const int t = threadIdx.x;
    const int m0 = mt * 128, n0 = nt * 128;

    const int lane = t & 63, wave = t >> 6;
    const int l15 = lane & 15, quad = lane >> 4;
    const int wm = wave & 1, wn = wave >> 1;
    const int sr = lane >> 3;
    const int sq = ((lane & 7) ^ sr) * 8;
    const int l7 = l15 & 7;

    const unsigned short* gA = Qb + (size_t)b * S_ * D_ + (size_t)(m0 + wave * 32 + sr) * D_ + sq;
    const unsigned short* gB = Kb + (size_t)b * S_ * D_ + (size_t)(n0 + wave * 32 + sr) * D_ + sq;
    unsigned short* lA = &As[wave * 2048];
    unsigned short* lB = &Bs[wave * 2048];

    f32x4 acc[4][4];
    #pragma unroll
    for (int i = 0; i < 4; i++)
        #pragma unroll
        for (int j = 0; j < 4; j++) acc[i][j] = {0.f, 0.f, 0.f, 0.f};

    for (int kt = 0; kt < 16; kt++) {
        const int k0 = kt * 64;
        __syncthreads();
        #pragma unroll
        for (int i = 0; i < 4; i++) {
            async16(gA + k0 + i * 8 * D_, lA + i * 512);
            async16(gB + k0 + i * 8 * D_, lB + i * 512);
        }
        __syncthreads();

        #pragma unroll
        for (int s = 0; s < 2; s++) {
            const int cs = ((s * 4 + quad) ^ l7) * 8;
            bf16x8 af[4], bfr[4];
            #pragma unroll
            for (int i = 0; i < 4; i++)
                af[i] = *(const bf16x8*)&As[(wm * 64 + i * 16 + l15) * 64 + cs];
            #pragma unroll
            for (int j = 0; j < 4; j++)
                bfr[j] = *(const bf16x8*)&Bs[(wn * 64 + j * 16 + l15) * 64 + cs];
            #pragma unroll
            for (int i = 0; i < 4; i++)
                #pragma unroll
                for (int j = 0; j < 4; j++)
                    acc[i][j] = __builtin_amdgcn_mfma_f32_16x16x32_bf16(af[i], bfr[j], acc[i][j], 0, 0, 0);
        }
    }

    unsigned short* Pb = P + (size_t)b * S_ * S_;
    #pragma unroll
    for (int i = 0; i < 4; i++)
        #pragma unroll
        for (int j = 0; j < 4; j++) {
            const int gn = n0 + wn * 64 + j * 16 + l15;
            #pragma unroll
            for (int r = 0; r < 4; r++) {
                const int gm = m0 + wm * 64 + i * 16 + quad * 4 + r;
                const float e = (gn <= gm) ? __expf(acc[i][j][r]) : 0.f;
                acc[i][j][r] = e;
                Pb[(size_t)gm * S_ + gn] = f2bf(e);
            }
        }

    float* rp = rowpart + ((size_t)b * 32 + nt * 2 + wn) * S_;
    #pragma unroll
    for (int i = 0; i < 4; i++) {
        float rsub[4];
        #pragma unroll
        for (int r = 0; r < 4; r++) {
            float s = acc[i][0][r] + acc[i][1][r] + acc[i][2][r] + acc[i][3][r];
            #pragma unroll
            for (int off = 8; off; off >>= 1) s += __shfl_xor(s, off);
            rsub[r] = s;
        }
        if (l15 == 0) {
            #pragma unroll
            for (int r = 0; r < 4; r++)
                rp[m0 + wm * 64 + i * 16 + quad * 4 + r] = rsub[r];
        }
    }

    __syncthreads();   // all threads' P/rowpart stores completed (vmcnt drain)
    if (t == 0) {
        __threadfence();   // agent fence: writeback producer XCD L2
        __hip_atomic_fetch_add(&done[b * 16 + mt], 1,
                               __ATOMIC_RELEASE, __HIP_MEMORY_SCOPE_AGENT);
    }
}

// ---------------------------------------------------------------------------
// pv tile: out = (E @ V) / rowsum. 128x128, BK=64, single-buf 32 KB (4/CU).
// Acquire-spins on done[b*16+mt]==mt+1, then agent fence (invalidate stale
// L1/L2 lines of P/rowpart) before the block reads them.
// ---------------------------------------------------------------------------
static __device__ __forceinline__
void do_pv(int pid, const unsigned short* P, const unsigned short* Vt,
           const float* rowpart, float* out, int* done,
           unsigned short* As, unsigned short* Bs)
{
    const int mt  = 15 - (pid >> 5);          // heavy-first
    const int rem = pid & 31;
    const int b   = rem >> 3;
    const int nt  = rem & 7;
    const int m0 = mt * 128, n0 = nt * 128;
    const int niter = 2 * mt + 2;             // kend = m0+128, BK=64

    const int t = threadIdx.x;
    if (t == 0) {
        while (__hip_atomic_load(&done[b * 16 + mt],
                                 __ATOMIC_ACQUIRE, __HIP_MEMORY_SCOPE_AGENT) < mt + 1)
            __builtin_amdgcn_s_sleep(8);
        __threadfence();                      // invalidate stale cached P/rowpart
    }
    __syncthreads();                          // deps ready for whole block

    const int lane = t & 63, wave = t >> 6;
    const int l15 = lane & 15, quad = lane >> 4;
    const int wm = wave & 1, wn = wave >> 1;
    const int sr = lane >> 3;
    const int sq = ((lane & 7) ^ sr) * 8;
    const int l7 = l15 & 7;

    const unsigned short* gA = P  + (size_t)b * S_ * S_ + (size_t)(m0 + wave * 32 + sr) * S_ + sq;
    const unsigned short* gB = Vt + (size_t)b * D_ * S_ + (size_t)(n0 + wave * 32 + sr) * S_ + sq;
    unsigned short* lA = &As[wave * 2048];
    unsigned short* lB = &Bs[wave * 2048];

    // 1/rowsum gather (rowpart complete once done==mt+1)
    const float* rp = rowpart + (size_t)b * 32 * S_ + (m0 + wm * 64 + lane);
    float rsum = 0.f;
    for (int k = 0; k < niter; k++) rsum += rp[(size_t)k * S_];
    const float invr = 1.0f / rsum;

    f32x4 acc[4][4];
    #pragma unroll
    for (int i = 0; i < 4; i++)
        #pragma unroll
        for (int j = 0; j < 4; j++) acc[i][j] = {0.f, 0.f, 0.f, 0.f};

    for (int kt = 0; kt < niter; kt++) {
        const int k0 = kt * 64;
        __syncthreads();
        #pragma unroll
        for (int i = 0; i < 4; i++) {
            async16(gA + k0 + i * 8 * S_, lA + i * 512);
            async16(gB + k0 + i * 8 * S_, lB + i * 512);
        }
        __syncthreads();

        #pragma unroll
        for (int s = 0; s < 2; s++) {
            const int cs = ((s * 4 + quad) ^ l7) * 8;
            bf16x8 af[4], bfr[4];
            #pragma unroll
            for (int i = 0; i < 4; i++)
                af[i] = *(const bf16x8*)&As[(wm * 64 + i * 16 + l15) * 64 + cs];
            #pragma unroll
            for (int j = 0; j < 4; j++)
                bfr[j] = *(const bf16x8*)&Bs[(wn * 64 + j * 16 + l15) * 64 + cs];
            #pragma unroll
            for (int i = 0; i < 4; i++)
                #pragma unroll
                for (int j = 0; j < 4; j++)
                    acc[i][j] = __builtin_amdgcn_mfma_f32_16x16x32_bf16(af[i], bfr[j], acc[i][j], 0, 0, 0);
        }
    }

    #pragma unroll
    for (int i = 0; i < 4; i++) {
        #pragma unroll
        for (int r = 0; r < 4; r++) {
            const float vr = __shfl(invr, i * 16 + quad * 4 + r);
            const int gm = m0 + wm * 64 + i * 16 + quad * 4 + r;
            #pragma unroll
            for (int j = 0; j < 4; j++) {
                const int gn = n0 + wn * 64 + j * 16 + l15;
                out[((size_t)b * S_ + gm) * D_ + gn] = rintf(acc[i][j][r] * vr * 1e4f) * 1e-4f;
            }
        }
    }
}

// ---------------------------------------------------------------------------
// Kernel 2 (PLAIN launch, 1024 blocks — all co-resident by capacity:
// LDS 32 KB -> 5/CU, waves 4@64VGPR -> 8/CU => >=4/CU x 256 CU = 1024):
//   blocks 0..543   : exp item (heavy-first); blocks 0..31 then take the 32
//                     lightest pv items (mt=0, 2 iters) as second items.
//   blocks 544..1023: pv items 0..479 (heavy-first).
// exp blocks never wait -> deadlock-free under any dispatch order.
// ---------------------------------------------------------------------------
__global__ __launch_bounds__(256, 4)
void attn_kernel(const unsigned short* __restrict__ Qb,
                 const unsigned short* __restrict__ Kb,
                 const unsigned short* __restrict__ Vt,
                 unsigned short* __restrict__ P,
                 float* __restrict__ rowpart,
                 float* __restrict__ out,
                 int* __restrict__ done)
{
    __shared__ __align__(16) unsigned short As[128 * 64];
    __shared__ __align__(16) unsigned short Bs[128 * 64];

    const int bid = blockIdx.x;
    if (bid < 544) {
        do_exp(bid, Qb, Kb, P, rowpart, done, As, Bs);
        if (bid < 32) do_pv(480 + bid, P, Vt, rowpart, out, done, As, Bs);
    } else {
        do_pv(bid - 544, P, Vt, rowpart, out, done, As, Bs);
    }
}

// ---------------------------------------------------------------------------
// Workspace (~85 MB + 256 B):
//   [0,     16.7M)  Qb bf16 [4][2048][1024]
//   [16.7M, 33.5M)  Kb bf16
//   [33.5M, 50.3M)  Vt bf16 [4][1024][2048]
//   [50.3M, 83.9M)  P  bf16 [4][2048][2048]
//       xb (16.7M) + Wb (6.3M) overlay the start of P's region (dead before
//       attn writes P).
//   [83.9M, +1M)    rowpart fp32 [4][32][2048]
//   [+1M,  +256B)   done int[64]  (zeroed by convert)
// ---------------------------------------------------------------------------
extern "C" void kernel_launch(void* const* d_in, const int* in_sizes, int n_in,
                              void* d_out, int out_size, void* d_ws, size_t ws_size,
                              hipStream_t stream)
{
    (void)in_sizes; (void)n_in; (void)out_size; (void)ws_size;
    const float* x  = (const float*)d_in[0];
    const float* Wk = (const float*)d_in[1];
    const float* Wq = (const float*)d_in[2];
    const float* Wv = (const float*)d_in[3];
    float* out = (float*)d_out;

    char* ws = (char*)d_ws;
    unsigned short* Qb = (unsigned short*)ws;
    unsigned short* Kb = Qb + (size_t)B_ * S_ * D_;
    unsigned short* Vt = Kb + (size_t)B_ * S_ * D_;
    unsigned short* P  = Vt + (size_t)B_ * D_ * S_;
    unsigned short* xb = P;                                  // overlay (dead early)
    unsigned short* Wb = xb + (size_t)B_ * S_ * E_;
    float* rowpart = (float*)(P + (size_t)B_ * S_ * S_);
    int* done = (int*)(rowpart + (size_t)B_ * 32 * S_);

    convert_kernel<<<2048, 256, 0, stream>>>(x, Wk, Wq, Wv, xb, Wb, done);
    proj_kernel   <<<dim3(64, 24, 1), 256, 0, stream>>>(xb, Wb, Qb, Kb, Vt);
    attn_kernel   <<<dim3(1024, 1, 1), 256, 0, stream>>>(Qb, Kb, Vt, P, rowpart, out, done);
}